// Round 13
// baseline (132.722 us; speedup 1.0000x reference)
//
#include <hip/hip_runtime.h>

// NodeEncoder with interpolation, round 13.
//
// Ledger — dead: nt-stores (R3 -12%), per-wave MLP (R4 -7%), barrier drain
// (R7 null), topology (R9 null), no-LDS strided stores (R10 -48%),
// occupancy 4/8/32 waves/CU (R11/R12/R5: flat). Confirmed: phase-separated
// prefetched reads (R5), contiguous wave-stores, zero-barrier 1-wave blocks
// (R11, 105.0 us / 5.18 TB/s best).
//
// R13: remove the last untested structure — the 2-level dependent LDS chain
// in the store path (ds_read_b32 z -> ds_read_b128 LUT row). Instead, at
// staging time each lane runs the 16-entry chain for its 4 staged atoms and
// writes an 8 B param record {whi, j|jl<<8} to LDS. Store loop: ONE
// broadcast conflict-free ds_read_b64 + ~25 VALU -> contiguous store.
// wlo is derived as 1-whi (<=1 ulp vs reference's division; threshold 2e-2;
// exact case gives wlo=0 exactly). No LUT; LDS = 4 KB.

#define K_TAB 16
#define WSZ   64
#define CA    256                  // atoms per wave-chunk (1 KB z, 16 KB out)
#define INNER (CA / 16)            // 16 store iterations per chunk

typedef float v4f __attribute__((ext_vector_type(4)));

// Branchless searchsorted chain for one (integer-valued) z.
// Returns {whi, bits(j | jl<<8)}.
__device__ __forceinline__ float2 atom_params(float z) {
    constexpr float tab[K_TAB] = {0.f, 1.f, 6.f, 7.f, 8.f, 11.f, 13.f, 14.f,
                                  16.f, 17.f, 26.f, 29.f, 47.f, 78.f, 79.f, 83.f};
    int j = 0;
    float zlo = tab[0];
    float zhi = tab[K_TAB - 1];
#pragma unroll
    for (int k = 0; k < K_TAB; ++k) {          // ascending: count < z, track z_lo
        const bool lt = (tab[k] < z);
        j += lt ? 1 : 0;
        zlo = lt ? tab[k] : zlo;
    }
#pragma unroll
    for (int k = K_TAB - 2; k >= 0; --k) {     // descending: smallest entry >= z
        zhi = (tab[k] >= z) ? tab[k] : zhi;
    }
    if (j > K_TAB - 1) j = K_TAB - 1;
    const bool exact = (zhi == z);
    const float denom = exact ? 1.f : (zhi - zlo);
    const float whi   = exact ? 1.f : (z - zlo) / denom;
    int jl = j - (exact ? 0 : 1);
    if (jl < 0) jl = 0;
    float2 r;
    r.x = whi;
    r.y = __uint_as_float((unsigned)j | ((unsigned)jl << 8));
    return r;
}

__device__ __forceinline__ v4f load_z4(const float* __restrict__ z_in,
                                       int c, int lane, int n_atoms) {
    const int a0 = c * CA + lane * 4;
    v4f r = {0.f, 0.f, 0.f, 0.f};
    if (a0 + 3 < n_atoms) {
        r = *reinterpret_cast<const v4f*>(&z_in[a0]);
    } else {
#pragma unroll
        for (int e = 0; e < 4; ++e)
            if (a0 + e < n_atoms) r[e] = z_in[a0 + e];
    }
    return r;   // OOB atoms -> z=0 -> exact row 0 (their stores are guarded)
}

// Compute + publish params for the 4 atoms in zv (lane-owned slot).
__device__ __forceinline__ void publish_params(float2* __restrict__ pmbuf,
                                               int lane, v4f zv) {
    const float2 q0 = atom_params(zv[0]);
    const float2 q1 = atom_params(zv[1]);
    const float2 q2 = atom_params(zv[2]);
    const float2 q3 = atom_params(zv[3]);
    v4f w0, w1;
    w0.x = q0.x; w0.y = q0.y; w0.z = q1.x; w0.w = q1.y;
    w1.x = q2.x; w1.y = q2.y; w1.z = q3.x; w1.w = q3.y;
    v4f* dst = reinterpret_cast<v4f*>(&pmbuf[lane * 4]);
    dst[0] = w0;
    dst[1] = w1;
}

__global__ __launch_bounds__(WSZ) void node_encode_kernel(
    const float* __restrict__ z_in,
    float* __restrict__ out,
    int n_atoms, int n_chunks)
{
    __shared__ float2 pm[2][CA];        // 2 x 2 KB param double buffer

    const int lane   = threadIdx.x;     // one wave per block
    const int nwaves = gridDim.x;
    const int gwave  = blockIdx.x;

    v4f* __restrict__ out4 = reinterpret_cast<v4f*>(out);

    // ---- prologue: params for first chunk ----
    int c = gwave;
    if (c < n_chunks) {
        const v4f z0 = load_z4(z_in, c, lane, n_atoms);
        publish_params(pm[0], lane, z0);
    }

    // ---- zero-barrier phase loop ----
    int p = 0;
    for (; c < n_chunks; c += nwaves, ++p) {
        // prefetch next chunk's z early; chains for it run after the stores
        const int cn = c + nwaves;
        const bool haveN = (cn < n_chunks);
        v4f zregN = {0.f, 0.f, 0.f, 0.f};
        if (haveN) zregN = load_z4(z_in, cn, lane, n_atoms);

        const float2* __restrict__ pmb = pm[p & 1];
        const long base4 = (long)c * (CA * 4);     // float4 index of chunk start
        const int  c0    = (lane & 3) << 2;        // this lane's column group
        if ((c + 1) * CA <= n_atoms) {
            // full chunk: 16 x (b64 broadcast read -> 25 VALU -> 1 KB store)
#pragma unroll
            for (int k = 0; k < INNER; ++k) {
                const float2 pp = pmb[k * 16 + (lane >> 2)];
                const float whi = pp.x;
                const unsigned d = __float_as_uint(pp.y);
                const int j  = d & 0xFF;
                const int jl = (d >> 8) & 0xFF;
                const float wlo = 1.f - whi;       // exact: whi=1 -> wlo=0
                const int rj = j - c0;
                const int rl = jl - c0;
                v4f v;
                v.x = (rj == 0 ? whi : 0.f) + (rl == 0 ? wlo : 0.f);
                v.y = (rj == 1 ? whi : 0.f) + (rl == 1 ? wlo : 0.f);
                v.z = (rj == 2 ? whi : 0.f) + (rl == 2 ? wlo : 0.f);
                v.w = (rj == 3 ? whi : 0.f) + (rl == 3 ? wlo : 0.f);
                out4[base4 + k * WSZ + lane] = v;
            }
        } else {
            const long total4 = (long)n_atoms * 4;
            for (int k = 0; k < INNER; ++k) {
                const long g = base4 + k * WSZ + lane;
                if (g < total4) {
                    const float2 pp = pmb[k * 16 + (lane >> 2)];
                    const float whi = pp.x;
                    const unsigned d = __float_as_uint(pp.y);
                    const int j  = d & 0xFF;
                    const int jl = (d >> 8) & 0xFF;
                    const float wlo = 1.f - whi;
                    const int rj = j - c0;
                    const int rl = jl - c0;
                    v4f v;
                    v.x = (rj == 0 ? whi : 0.f) + (rl == 0 ? wlo : 0.f);
                    v.y = (rj == 1 ? whi : 0.f) + (rl == 1 ? wlo : 0.f);
                    v.z = (rj == 2 ? whi : 0.f) + (rl == 2 ? wlo : 0.f);
                    v.w = (rj == 3 ? whi : 0.f) + (rl == 3 ? wlo : 0.f);
                    out4[g] = v;
                }
            }
        }

        if (haveN) {
            publish_params(pm[(p + 1) & 1], lane, zregN);   // overlaps store drain
        }
    }
}

extern "C" void kernel_launch(void* const* d_in, const int* in_sizes, int n_in,
                              void* d_out, int out_size, void* d_ws, size_t ws_size,
                              hipStream_t stream) {
    const float* z = (const float*)d_in[0];
    float* out = (float*)d_out;
    const int n_atoms = in_sizes[0];

    const int n_chunks = (n_atoms + CA - 1) / CA;   // 31250 for 8M atoms
    const int grid = 1024;                          // 4 single-wave blocks/CU (R11 best)

    node_encode_kernel<<<grid, WSZ, 0, stream>>>(z, out, n_atoms, n_chunks);
}

// Round 14
// 104.911 us; speedup vs baseline: 1.2651x; 1.2651x over previous
//
#include <hip/hip_runtime.h>

// NodeEncoder with interpolation, round 14.
//
// Ledger — dead: nt-stores (R3 -12%), per-wave MLP (R4 -7%), barrier drain
// (R7 null), topology (R9 null), no-LDS strided stores (R10 -48%),
// occupancy 4/8/32 waves/CU (flat), VALU row-reconstruction in store loop
// (R13 -26%). Confirmed: phase-separated prefetched reads (R5), LDS
// LUT-gather + contiguous wave-stores, zero-barrier 1-wave blocks
// (R11 best: 105.0 us / 5.18 TB/s).
//
// R14 single change: LUT row stride 16 -> 20 floats (80 B, still 16B-aligned
// for ds_read_b128). With 64 B rows, row zi occupies banks 16*(zi&1)..+15:
// the wave's 16 random-row groups split into two parity classes that each
// collide ~8-way on the same 16 banks (m136: 8-way = 2.94x). Stride-20 rows
// start at bank (20*zi)%32 (period 8), spreading groups across 8 offsets ->
// ~2-way (free). Everything else byte-identical to R11.

#define K_TAB  16
#define LUT_W  20                  // padded row stride (floats): bank spread
#define N_Z    83
#define WSZ    64
#define CA     256                 // atoms per wave-chunk (1 KB z, 16 KB out)
#define INNER  (CA / 16)           // 16 store iterations per chunk

typedef float v4f __attribute__((ext_vector_type(4)));

__global__ __launch_bounds__(WSZ) void node_encode_kernel(
    const float* __restrict__ z_in,
    float* __restrict__ out,
    int n_atoms, int n_chunks)
{
    __shared__ float lut[N_Z][LUT_W];   // 6.6 KB, rows 80 B apart
    __shared__ float zl[2][CA];         // 2 x 1 KB, single-wave owned

    const int lane = threadIdx.x;       // one wave per block

    // ---- LUT init: rows lane and lane+64 (single wave, no barrier needed) ----
    constexpr float tab[K_TAB] = {0.f, 1.f, 6.f, 7.f, 8.f, 11.f, 13.f, 14.f,
                                  16.f, 17.f, 26.f, 29.f, 47.f, 78.f, 79.f, 83.f};
    for (int row = lane; row < N_Z; row += WSZ) {
        const float zf = (float)row;
        int j = 0;
        float zlo = tab[0];
        float zhi = tab[K_TAB - 1];
#pragma unroll
        for (int k = 0; k < K_TAB; ++k) {          // ascending: count < z, track z_lo
            const bool lt = (tab[k] < zf);
            j += lt ? 1 : 0;
            zlo = lt ? tab[k] : zlo;
        }
#pragma unroll
        for (int k = K_TAB - 2; k >= 0; --k) {     // descending: smallest entry >= z
            zhi = (tab[k] >= zf) ? tab[k] : zhi;
        }
        const bool exact = (zhi == zf);
        const float denom = exact ? 1.f : (zhi - zlo);
        const float inv   = 1.f / denom;
        const float whi   = exact ? 1.f : (zf - zlo) * inv;
        const float wlo   = exact ? 0.f : (zhi - zf) * inv;
        int jl = j - (exact ? 0 : 1);
        if (jl < 0) jl = 0;
#pragma unroll
        for (int c = 0; c < K_TAB; ++c) {
            lut[row][c] = (c == j ? whi : 0.f) + (c == jl ? wlo : 0.f);
        }
    }

    v4f* __restrict__ out4 = reinterpret_cast<v4f*>(out);
    const int nwaves = gridDim.x;       // 1 wave per block
    const int gwave  = blockIdx.x;

    // ---- prologue: load first chunk's z into registers ----
    int c = gwave;
    v4f zreg = {0.f, 0.f, 0.f, 0.f};
    if (c < n_chunks) {
        const int a0 = c * CA + lane * 4;
        if (a0 + 3 < n_atoms) {
            zreg = *reinterpret_cast<const v4f*>(&z_in[a0]);
        } else {
#pragma unroll
            for (int e = 0; e < 4; ++e)
                if (a0 + e < n_atoms) zreg[e] = z_in[a0 + e];
        }
    }

    // ---- zero-barrier phase loop ----
    int p = 0;
    for (; c < n_chunks; c += nwaves, ++p) {
        // publish current chunk's z (wave-private buffer; lgkmcnt orders RAW)
        *reinterpret_cast<v4f*>(&zl[p & 1][lane * 4]) = zreg;

        // prefetch next chunk's z under the store run
        const int cn = c + nwaves;
        if (cn < n_chunks) {
            const int a0 = cn * CA + lane * 4;
            if (a0 + 3 < n_atoms) {
                zreg = *reinterpret_cast<const v4f*>(&z_in[a0]);
            } else {
                v4f zt = {0.f, 0.f, 0.f, 0.f};
#pragma unroll
                for (int e = 0; e < 4; ++e)
                    if (a0 + e < n_atoms) zt[e] = z_in[a0 + e];
                zreg = zt;
            }
        }

        const float* __restrict__ zb = zl[p & 1];
        const long base4 = (long)c * (CA * 4);     // float4 index of chunk start
        if ((c + 1) * CA <= n_atoms) {
            // full chunk: 16 x (zi -> lut b128 -> contiguous 1 KB wave-store)
#pragma unroll
            for (int k = 0; k < INNER; ++k) {
                const int u  = k * WSZ + lane;
                const int zi = (int)zb[u >> 2];
                const v4f v  = *reinterpret_cast<const v4f*>(&lut[zi][(u & 3) << 2]);
                out4[base4 + u] = v;
            }
        } else {
            const long total4 = (long)n_atoms * 4;
            for (int k = 0; k < INNER; ++k) {
                const int u = k * WSZ + lane;
                const long g = base4 + u;
                if (g < total4) {
                    const int zi = (int)zb[u >> 2];
                    out4[g] = *reinterpret_cast<const v4f*>(&lut[zi][(u & 3) << 2]);
                }
            }
        }
    }
}

extern "C" void kernel_launch(void* const* d_in, const int* in_sizes, int n_in,
                              void* d_out, int out_size, void* d_ws, size_t ws_size,
                              hipStream_t stream) {
    const float* z = (const float*)d_in[0];
    float* out = (float*)d_out;
    const int n_atoms = in_sizes[0];

    const int n_chunks = (n_atoms + CA - 1) / CA;   // 31250 for 8M atoms
    const int grid = 1024;                          // 4 single-wave blocks/CU (R11 best)

    node_encode_kernel<<<grid, WSZ, 0, stream>>>(z, out, n_atoms, n_chunks);
}